// Round 6
// baseline (48.125 us; speedup 1.0000x reference)
//
#include <hip/hip_runtime.h>

// TopKRouter: x[B=16,C=768,H=64,W=64] fp32, W[E=16,C=768], b[E=16], k=2.
// R6: ONE fused kernel. R4's inner structure (float2/lane, 4 channel-groups x
// 128 px/block, 512 blocks = 2/CU) — but W is transposed into LDS at block
// start (conflict-free pattern), removing the transpose prologue kernel and
// its launch/dependency gap (~5 us of R4's 41.3).
// Cross-wave reduce: 4-step sequential accumulate into [128][17] LDS buffer
// (Wt 48 KB + red 8.7 KB = 57.9 KB < 64 KB static, 2 blocks/CU).
// Outputs fp32 concat: topk_probs[16,2,64,64] | topk_indices[16,2,64,64] |
// scores[16,16,64,64].

#define C_DIM 768
#define E_DIM 16
#define HW    4096   // 64*64
#define NPIX  65536  // 16*4096

__global__ __launch_bounds__(256) void router_fused(
    const float* __restrict__ x,     // [B, C, HW]
    const float* __restrict__ Wm,    // [E, C]
    const float* __restrict__ bias,  // [E]
    float* __restrict__ out)
{
    __shared__ float wt[C_DIM][E_DIM];   // 48 KB, transposed weights
    __shared__ float red[128][17];       // 8.7 KB, cross-wave reduce (pad 17)

    // ---- W transpose into LDS, conflict-free ----
    // thread t -> e = t&15, c = (t>>4) + 16j. LDS write bank = t%32.
    {
        const int e  = threadIdx.x & 15;
        const int cb = threadIdx.x >> 4;  // 0..15
#pragma unroll
        for (int j = 0; j < 48; ++j) {
            const int c = cb + (j << 4);
            wt[c][e] = Wm[e * C_DIM + c];
        }
    }
    __syncthreads();

    const int p0  = blockIdx.x * 128;            // first pixel of block
    const int b   = p0 >> 12;                    // batch (block-uniform)
    const int pb  = p0 & 4095;
    const int cg  = __builtin_amdgcn_readfirstlane(threadIdx.x >> 6);
    const int px2 = threadIdx.x & 63;            // lane -> pixel pair
    const int c0  = cg * 192;

    const float* xp = x + (size_t)b * C_DIM * HW + pb + 2 * px2;

    float2 acc[E_DIM];
#pragma unroll
    for (int e = 0; e < E_DIM; ++e) acc[e] = make_float2(0.f, 0.f);

#pragma unroll 4
    for (int c = c0; c < c0 + 192; ++c) {
        const float2 xv = *reinterpret_cast<const float2*>(xp + (size_t)c * HW);
        const float4* wr = reinterpret_cast<const float4*>(&wt[c][0]);  // uniform -> broadcast
        const float4 w0 = wr[0], w1 = wr[1], w2 = wr[2], w3 = wr[3];
        acc[ 0].x = fmaf(xv.x, w0.x, acc[ 0].x); acc[ 0].y = fmaf(xv.y, w0.x, acc[ 0].y);
        acc[ 1].x = fmaf(xv.x, w0.y, acc[ 1].x); acc[ 1].y = fmaf(xv.y, w0.y, acc[ 1].y);
        acc[ 2].x = fmaf(xv.x, w0.z, acc[ 2].x); acc[ 2].y = fmaf(xv.y, w0.z, acc[ 2].y);
        acc[ 3].x = fmaf(xv.x, w0.w, acc[ 3].x); acc[ 3].y = fmaf(xv.y, w0.w, acc[ 3].y);
        acc[ 4].x = fmaf(xv.x, w1.x, acc[ 4].x); acc[ 4].y = fmaf(xv.y, w1.x, acc[ 4].y);
        acc[ 5].x = fmaf(xv.x, w1.y, acc[ 5].x); acc[ 5].y = fmaf(xv.y, w1.y, acc[ 5].y);
        acc[ 6].x = fmaf(xv.x, w1.z, acc[ 6].x); acc[ 6].y = fmaf(xv.y, w1.z, acc[ 6].y);
        acc[ 7].x = fmaf(xv.x, w1.w, acc[ 7].x); acc[ 7].y = fmaf(xv.y, w1.w, acc[ 7].y);
        acc[ 8].x = fmaf(xv.x, w2.x, acc[ 8].x); acc[ 8].y = fmaf(xv.y, w2.x, acc[ 8].y);
        acc[ 9].x = fmaf(xv.x, w2.y, acc[ 9].x); acc[ 9].y = fmaf(xv.y, w2.y, acc[ 9].y);
        acc[10].x = fmaf(xv.x, w2.z, acc[10].x); acc[10].y = fmaf(xv.y, w2.z, acc[10].y);
        acc[11].x = fmaf(xv.x, w2.w, acc[11].x); acc[11].y = fmaf(xv.y, w2.w, acc[11].y);
        acc[12].x = fmaf(xv.x, w3.x, acc[12].x); acc[12].y = fmaf(xv.y, w3.x, acc[12].y);
        acc[13].x = fmaf(xv.x, w3.y, acc[13].x); acc[13].y = fmaf(xv.y, w3.y, acc[13].y);
        acc[14].x = fmaf(xv.x, w3.z, acc[14].x); acc[14].y = fmaf(xv.y, w3.z, acc[14].y);
        acc[15].x = fmaf(xv.x, w3.w, acc[15].x); acc[15].y = fmaf(xv.y, w3.w, acc[15].y);
    }

    // ---- sequential cross-wave accumulate (wave-uniform branch) ----
    __syncthreads();  // all waves done with wt-phase timing; red safe to use
#pragma unroll
    for (int s = 0; s < 4; ++s) {
        if (cg == s) {
            if (s == 0) {
#pragma unroll
                for (int e = 0; e < E_DIM; ++e) {
                    red[2 * px2][e]     = acc[e].x;
                    red[2 * px2 + 1][e] = acc[e].y;
                }
            } else {
#pragma unroll
                for (int e = 0; e < E_DIM; ++e) {
                    red[2 * px2][e]     += acc[e].x;
                    red[2 * px2 + 1][e] += acc[e].y;
                }
            }
        }
        __syncthreads();
    }

    // ---- epilogue: softmax + top2, threads 0..127 (one px each) ----
    const int t = threadIdx.x;
    if (t < 128) {
        const int p = pb + t;

        float lg[E_DIM];
#pragma unroll
        for (int e = 0; e < E_DIM; ++e) lg[e] = bias[e] + red[t][e];

        float m = -INFINITY;
#pragma unroll
        for (int e = 0; e < E_DIM; ++e) m = fmaxf(m, lg[e]);
        float pr[E_DIM];
        float sum = 0.0f;
#pragma unroll
        for (int e = 0; e < E_DIM; ++e) {
            pr[e] = __expf(lg[e] - m);
            sum += pr[e];
        }
        const float inv = 1.0f / sum;

        float* scores = out + 262144;
#pragma unroll
        for (int e = 0; e < E_DIM; ++e) {
            const float s = pr[e] * inv;
            pr[e] = s;
            scores[(size_t)(b * E_DIM + e) * HW + p] = s;
        }

        // top-2, ties -> lower index (matches jax.lax.top_k)
        int i1 = 0;
        float p1 = pr[0];
#pragma unroll
        for (int e = 1; e < E_DIM; ++e)
            if (pr[e] > p1) { p1 = pr[e]; i1 = e; }
        int i2 = -1;
        float p2 = -INFINITY;
#pragma unroll
        for (int e = 0; e < E_DIM; ++e)
            if (e != i1 && pr[e] > p2) { p2 = pr[e]; i2 = e; }

        const float rs = 1.0f / (p1 + p2);
        const size_t o1 = (size_t)(b * 2 + 0) * HW + p;
        const size_t o2 = (size_t)(b * 2 + 1) * HW + p;
        out[o1] = p1 * rs;
        out[o2] = p2 * rs;
        float* idxo = out + 131072;
        idxo[o1] = (float)i1;
        idxo[o2] = (float)i2;
    }
}

extern "C" void kernel_launch(void* const* d_in, const int* in_sizes, int n_in,
                              void* d_out, int out_size, void* d_ws, size_t ws_size,
                              hipStream_t stream) {
    const float* x  = (const float*)d_in[0];
    const float* Wm = (const float*)d_in[1];
    const float* bs = (const float*)d_in[2];
    float* out = (float*)d_out;

    router_fused<<<NPIX / 128, 256, 0, stream>>>(x, Wm, bs, out);
}